// Round 1
// baseline (514.827 us; speedup 1.0000x reference)
//
#include <hip/hip_runtime.h>

#define LOG2E 1.44269504088896340736f

struct Params {
  const float* x[4]; const float* f[4]; const float* kvw[4]; const float* kvb[4];
  const float* pw[4]; const float* pb[4]; const float* g[4]; const float* lb[4];
  float* kb[4]; float* vb[4]; float* ob[4]; float* out[4];
};

__device__ inline float dot4(float4 a, float4 b) {
  return fmaf(a.w, b.w, fmaf(a.z, b.z, fmaf(a.y, b.y, a.x * b.x)));
}
__device__ inline void fma4(float4& a, float p, float4 v) {
  a.x = fmaf(p, v.x, a.x); a.y = fmaf(p, v.y, a.y);
  a.z = fmaf(p, v.z, a.z); a.w = fmaf(p, v.w, a.w);
}
__device__ inline void scale4(float4& a, float r) { a.x *= r; a.y *= r; a.z *= r; a.w *= r; }

// ---------------- KV projection: out[n][j] = f[n,:] . kv_w[j,:] + kv_b[j] ----------------
__global__ __launch_bounds__(256) void kv_all(Params P) {
  int bid = blockIdx.x;
  int s, local;
  if (bid < 8)       { s = 0; local = bid; }
  else if (bid < 24) { s = 1; local = bid - 8; }
  else if (bid < 56) { s = 2; local = bid - 24; }
  else               { s = 3; local = bid - 56; }
  const int C = 32 << s;
  int nt = local & 7, jt = local >> 3;
  int n0 = nt * 64, j0 = jt * 64;
  const float* __restrict__ f = P.f[s];
  const float* __restrict__ w = P.kvw[s];
  __shared__ float fa[64][17];
  __shared__ float wb[64][17];
  int t = threadIdx.x;
  int ti = t & 15, tj = t >> 4;
  float acc[4][4];
  #pragma unroll
  for (int a = 0; a < 4; a++)
    #pragma unroll
    for (int b = 0; b < 4; b++) acc[a][b] = 0.f;

  for (int k0 = 0; k0 < C; k0 += 16) {
    __syncthreads();
    for (int i = t; i < 1024; i += 256) {
      int r = i >> 4, kk = i & 15;
      fa[r][kk] = f[(n0 + r) * C + k0 + kk];
      wb[r][kk] = w[(j0 + r) * C + k0 + kk];
    }
    __syncthreads();
    #pragma unroll
    for (int kk = 0; kk < 16; ++kk) {
      float av[4], bv[4];
      #pragma unroll
      for (int ii = 0; ii < 4; ii++) av[ii] = fa[ti * 4 + ii][kk];
      #pragma unroll
      for (int jj = 0; jj < 4; jj++) bv[jj] = wb[tj * 4 + jj][kk];
      #pragma unroll
      for (int ii = 0; ii < 4; ii++)
        #pragma unroll
        for (int jj = 0; jj < 4; jj++)
          acc[ii][jj] = fmaf(av[ii], bv[jj], acc[ii][jj]);
    }
  }
  const float* __restrict__ bias = P.kvb[s];
  float* kb = P.kb[s]; float* vb = P.vb[s];
  #pragma unroll
  for (int ii = 0; ii < 4; ii++) {
    int n = n0 + ti * 4 + ii;
    #pragma unroll
    for (int jj = 0; jj < 4; jj++) {
      int j = j0 + tj * 4 + jj;
      float val = acc[ii][jj] + bias[j];
      if (j < C) {
        kb[((j >> 4) * 512 + n) * 16 + (j & 15)] = val;
      } else {
        int j2 = j - C;
        vb[((j2 >> 4) * 512 + n) * 16 + (j2 & 15)] = val;
      }
    }
  }
}

// ---------------- Attention: one (stage, head, 256-row tile) per block ----------------
template <int C, int H>
__device__ void attn_stage(const Params& P, int s, int local, float4 (*kv)[512][4]) {
  constexpr int ROWS = 2 * ((C == 32) ? 32768 : (C == 64) ? 4096 : (C == 128) ? 512 : 64);
  int tile = local / H, head = local % H;
  const float* kh = P.kb[s] + head * 8192;  // 512*16 floats per head
  const float* vh = P.vb[s] + head * 8192;
  int t = threadIdx.x;
  for (int i = t; i < 2048; i += 256) {
    kv[0][i >> 2][i & 3] = ((const float4*)kh)[i];
    kv[1][i >> 2][i & 3] = ((const float4*)vh)[i];
  }
  __syncthreads();
  int row = tile * 256 + t;
  if (row >= ROWS) return;

  const float* xr = P.x[s] + (size_t)row * C + head * 16;
  float4 q0 = ((const float4*)xr)[0], q1 = ((const float4*)xr)[1],
         q2 = ((const float4*)xr)[2], q3 = ((const float4*)xr)[3];
  const float qs = 0.25f * LOG2E;  // head_dim^-0.5 folded with log2(e)
  scale4(q0, qs); scale4(q1, qs); scale4(q2, qs); scale4(q3, qs);

  float m = -1e30f, l = 0.f;
  float4 a0 = {0,0,0,0}, a1 = {0,0,0,0}, a2 = {0,0,0,0}, a3 = {0,0,0,0};

  #pragma unroll 2
  for (int key = 0; key < 512; ++key) {
    float4 k0 = kv[0][key][0], k1 = kv[0][key][1], k2 = kv[0][key][2], k3 = kv[0][key][3];
    float s0 = dot4(q0, k0), s1 = dot4(q1, k1), s2 = dot4(q2, k2), s3 = dot4(q3, k3);
    float sc = (s0 + s1) + (s2 + s3);  // score in log2 units
    if (__any(sc > m + 8.f)) {         // defer-max: rare after first key
      float mn = fmaxf(m, sc);
      float r = __builtin_amdgcn_exp2f(m - mn);
      l *= r;
      scale4(a0, r); scale4(a1, r); scale4(a2, r); scale4(a3, r);
      m = mn;
    }
    float p = __builtin_amdgcn_exp2f(sc - m);
    l += p;
    float4 v0 = kv[1][key][0], v1 = kv[1][key][1], v2 = kv[1][key][2], v3 = kv[1][key][3];
    fma4(a0, p, v0); fma4(a1, p, v1); fma4(a2, p, v2); fma4(a3, p, v3);
  }
  float inv = 1.f / l;
  scale4(a0, inv); scale4(a1, inv); scale4(a2, inv); scale4(a3, inv);
  float* orow = P.ob[s] + (size_t)row * C + head * 16;
  ((float4*)orow)[0] = a0; ((float4*)orow)[1] = a1;
  ((float4*)orow)[2] = a2; ((float4*)orow)[3] = a3;
}

__global__ __launch_bounds__(256, 2) void attn_all(Params P) {
  __shared__ float4 kvlds[2][512][4];  // 64 KB: K and V for one head
  int bid = blockIdx.x;
  if (bid < 512)      attn_stage<32, 2>(P, 0, bid, kvlds);
  else if (bid < 640) attn_stage<64, 4>(P, 1, bid - 512, kvlds);
  else if (bid < 672) attn_stage<128, 8>(P, 2, bid - 640, kvlds);
  else                attn_stage<256, 16>(P, 3, bid - 672, kvlds);
}

// ---------------- Proj + residual + LayerNorm: 64 rows per block ----------------
template <int C>
__device__ void proj_stage(const Params& P, int s, int tile, float* olds) {
  constexpr int CP = C + 4;      // +4 floats keeps 16B alignment, breaks bank aliasing
  constexpr int R = 256 / C;     // row-groups per pass
  constexpr int NR = C / 4;      // rows per thread
  int r0 = tile * 64;
  int t = threadIdx.x;
  const float* __restrict__ ob = P.ob[s];
  for (int i = t; i < 64 * (C / 4); i += 256) {
    int row = i / (C / 4), kk = i % (C / 4);
    ((float4*)(olds + row * CP))[kk] = ((const float4*)(ob + (size_t)(r0 + row) * C))[kk];
  }
  __syncthreads();
  int j = t % C, rg = t / C;
  const float* __restrict__ pw = P.pw[s];
  float acc[NR];
  #pragma unroll
  for (int i = 0; i < NR; ++i) acc[i] = 0.f;
  for (int k = 0; k < C; k += 4) {
    float4 w4 = *(const float4*)(pw + (size_t)j * C + k);
    #pragma unroll
    for (int i = 0; i < NR; ++i) {
      float4 o4 = *(const float4*)(olds + (rg + i * R) * CP + k);
      acc[i] = fmaf(o4.x, w4.x, acc[i]);
      acc[i] = fmaf(o4.y, w4.y, acc[i]);
      acc[i] = fmaf(o4.z, w4.z, acc[i]);
      acc[i] = fmaf(o4.w, w4.w, acc[i]);
    }
  }
  __syncthreads();  // all proj reads of olds done
  float pbj = P.pb[s][j];
  const float* __restrict__ x = P.x[s];
  #pragma unroll
  for (int i = 0; i < NR; ++i) {
    int r = rg + i * R;
    float xv = x[(size_t)(r0 + r) * C + j];
    olds[r * CP + j] = 0.5f * (acc[i] + pbj) + 0.5f * xv;
  }
  __syncthreads();
  // LayerNorm: one wave handles 16 rows
  int lane = t & 63, wv = t >> 6;
  const float* __restrict__ g = P.g[s];
  const float* __restrict__ lb = P.lb[s];
  float* __restrict__ out = P.out[s];
  for (int rr = 0; rr < 16; ++rr) {
    int r = wv * 16 + rr;
    float sum = 0.f, sq = 0.f;
    #pragma unroll
    for (int ch = lane; ch < C; ch += 64) {
      float v = olds[r * CP + ch];
      sum += v; sq = fmaf(v, v, sq);
    }
    #pragma unroll
    for (int o = 32; o; o >>= 1) { sum += __shfl_xor(sum, o); sq += __shfl_xor(sq, o); }
    float mu = sum * (1.f / C);
    float var = sq * (1.f / C) - mu * mu;
    float rstd = rsqrtf(var + 1e-5f);
    for (int ch = lane; ch < C; ch += 64) {
      float v = (olds[r * CP + ch] - mu) * rstd;
      out[(size_t)(r0 + r) * C + ch] = fmaf(v, g[ch], lb[ch]);
    }
  }
}

__global__ __launch_bounds__(256, 2) void proj_ln_all(Params P) {
  extern __shared__ float olds[];
  int bid = blockIdx.x;
  if (bid < 1024)      proj_stage<32>(P, 0, bid, olds);
  else if (bid < 1152) proj_stage<64>(P, 1, bid - 1024, olds);
  else if (bid < 1168) proj_stage<128>(P, 2, bid - 1152, olds);
  else                 proj_stage<256>(P, 3, bid - 1168, olds);
}

extern "C" void kernel_launch(void* const* d_in, const int* in_sizes, int n_in,
                              void* d_out, int out_size, void* d_ws, size_t ws_size,
                              hipStream_t stream) {
  Params P;
  float* ws = (float*)d_ws;
  float* out = (float*)d_out;
  // ws layout (floats): K/V per stage, then attention-output buffers
  const size_t kvoff[4]  = {0, 32768, 98304, 229376};
  const size_t ksz[4]    = {16384, 32768, 65536, 131072};      // 512*c
  const size_t ooff[4]   = {491520, 2588672, 3112960, 3244032};
  const size_t outoff[4] = {0, 2097152, 2621440, 2752512};
  for (int i = 0; i < 4; ++i) {
    const int b = i * 8;
    P.x[i]   = (const float*)d_in[b + 0];
    P.f[i]   = (const float*)d_in[b + 1];
    P.kvw[i] = (const float*)d_in[b + 2];
    P.kvb[i] = (const float*)d_in[b + 3];
    P.pw[i]  = (const float*)d_in[b + 4];
    P.pb[i]  = (const float*)d_in[b + 5];
    P.g[i]   = (const float*)d_in[b + 6];
    P.lb[i]  = (const float*)d_in[b + 7];
    P.kb[i]  = ws + kvoff[i];
    P.vb[i]  = ws + kvoff[i] + ksz[i];
    P.ob[i]  = ws + ooff[i];
    P.out[i] = out + outoff[i];
  }
  // passthrough outputs (x4, x5)
  hipMemcpyAsync(out + 2785280, d_in[32], 5120 * sizeof(float), hipMemcpyDeviceToDevice, stream);
  hipMemcpyAsync(out + 2790400, d_in[33], 640 * sizeof(float), hipMemcpyDeviceToDevice, stream);

  kv_all<<<120, 256, 0, stream>>>(P);
  attn_all<<<688, 256, 0, stream>>>(P);
  proj_ln_all<<<1170, 256, 66560, stream>>>(P);
}

// Round 2
// 355.113 us; speedup vs baseline: 1.4498x; 1.4498x over previous
//
#include <hip/hip_runtime.h>

#define LOG2E 1.44269504088896340736f

struct Params {
  const float* x[4]; const float* f[4]; const float* kvw[4]; const float* kvb[4];
  const float* pw[4]; const float* pb[4]; const float* g[4]; const float* lb[4];
  float* kb[4]; float* vb[4]; float* ob[4]; float* out[4];
};

__device__ inline float dot4(float4 a, float4 b) {
  return fmaf(a.w, b.w, fmaf(a.z, b.z, fmaf(a.y, b.y, a.x * b.x)));
}
__device__ inline void fma4(float4& a, float p, float4 v) {
  a.x = fmaf(p, v.x, a.x); a.y = fmaf(p, v.y, a.y);
  a.z = fmaf(p, v.z, a.z); a.w = fmaf(p, v.w, a.w);
}
__device__ inline void scale4(float4& a, float r) { a.x *= r; a.y *= r; a.z *= r; a.w *= r; }

// ---------------- KV projection: out[n][j] = f[n,:] . kv_w[j,:] + kv_b[j] ----------------
__global__ __launch_bounds__(256) void kv_all(Params P) {
  int bid = blockIdx.x;
  int s, local;
  if (bid < 8)       { s = 0; local = bid; }
  else if (bid < 24) { s = 1; local = bid - 8; }
  else if (bid < 56) { s = 2; local = bid - 24; }
  else               { s = 3; local = bid - 56; }
  const int C = 32 << s;
  int nt = local & 7, jt = local >> 3;
  int n0 = nt * 64, j0 = jt * 64;
  const float* __restrict__ f = P.f[s];
  const float* __restrict__ w = P.kvw[s];
  __shared__ float fa[64][17];
  __shared__ float wb[64][17];
  int t = threadIdx.x;
  int ti = t & 15, tj = t >> 4;
  float acc[4][4];
  #pragma unroll
  for (int a = 0; a < 4; a++)
    #pragma unroll
    for (int b = 0; b < 4; b++) acc[a][b] = 0.f;

  for (int k0 = 0; k0 < C; k0 += 16) {
    __syncthreads();
    for (int i = t; i < 1024; i += 256) {
      int r = i >> 4, kk = i & 15;
      fa[r][kk] = f[(n0 + r) * C + k0 + kk];
      wb[r][kk] = w[(j0 + r) * C + k0 + kk];
    }
    __syncthreads();
    #pragma unroll
    for (int kk = 0; kk < 16; ++kk) {
      float av[4], bv[4];
      #pragma unroll
      for (int ii = 0; ii < 4; ii++) av[ii] = fa[ti * 4 + ii][kk];
      #pragma unroll
      for (int jj = 0; jj < 4; jj++) bv[jj] = wb[tj * 4 + jj][kk];
      #pragma unroll
      for (int ii = 0; ii < 4; ii++)
        #pragma unroll
        for (int jj = 0; jj < 4; jj++)
          acc[ii][jj] = fmaf(av[ii], bv[jj], acc[ii][jj]);
    }
  }
  const float* __restrict__ bias = P.kvb[s];
  float* kb = P.kb[s]; float* vb = P.vb[s];
  #pragma unroll
  for (int ii = 0; ii < 4; ii++) {
    int n = n0 + ti * 4 + ii;
    #pragma unroll
    for (int jj = 0; jj < 4; jj++) {
      int j = j0 + tj * 4 + jj;
      float val = acc[ii][jj] + bias[j];
      if (j < C) {
        kb[((j >> 4) * 512 + n) * 16 + (j & 15)] = val;
      } else {
        int j2 = j - C;
        vb[((j2 >> 4) * 512 + n) * 16 + (j2 & 15)] = val;
      }
    }
  }
}

// ---------------- Attention: one (stage, head, 256-row tile) per block ----------------
// K/V streamed through a 16 KB LDS chunk (128 keys), register-prefetched.
template <int C, int H>
__device__ void attn_stage(const Params& P, int s, int local, float4* kvl) {
  constexpr int ROWS = 2 * ((C == 32) ? 32768 : (C == 64) ? 4096 : (C == 128) ? 512 : 64);
  int tile = local / H, head = local % H;
  const float4* __restrict__ kh = (const float4*)(P.kb[s] + head * 8192);
  const float4* __restrict__ vh = (const float4*)(P.vb[s] + head * 8192);
  int t = threadIdx.x;
  int row = tile * 256 + t;
  bool valid = row < ROWS;
  int rc = valid ? row : (ROWS - 1);

  const float* xr = P.x[s] + (size_t)rc * C + head * 16;
  float4 q0 = ((const float4*)xr)[0], q1 = ((const float4*)xr)[1],
         q2 = ((const float4*)xr)[2], q3 = ((const float4*)xr)[3];
  const float qs = 0.25f * LOG2E;  // head_dim^-0.5 folded with log2(e)
  scale4(q0, qs); scale4(q1, qs); scale4(q2, qs); scale4(q3, qs);

  float m = -1e30f, l = 0.f;
  float4 a0 = {0,0,0,0}, a1 = {0,0,0,0}, a2 = {0,0,0,0}, a3 = {0,0,0,0};

  // prefetch chunk 0 (512 float4 of K, 512 of V per chunk; 4 float4/thread)
  float4 pk0 = kh[t], pk1 = kh[t + 256], pv0 = vh[t], pv1 = vh[t + 256];
  kvl[t] = pk0; kvl[t + 256] = pk1; kvl[512 + t] = pv0; kvl[512 + t + 256] = pv1;

  for (int c = 0; c < 4; ++c) {
    if (c < 3) {  // issue next-chunk loads early; HBM/L2 latency hides under compute
      const float4* kp = kh + (c + 1) * 512;
      const float4* vp = vh + (c + 1) * 512;
      pk0 = kp[t]; pk1 = kp[t + 256]; pv0 = vp[t]; pv1 = vp[t + 256];
    }
    __syncthreads();  // LDS chunk c visible
    #pragma unroll 2
    for (int key = 0; key < 128; ++key) {
      float4 k0 = kvl[key * 4 + 0], k1 = kvl[key * 4 + 1],
             k2 = kvl[key * 4 + 2], k3 = kvl[key * 4 + 3];
      float s0 = dot4(q0, k0), s1 = dot4(q1, k1), s2 = dot4(q2, k2), s3 = dot4(q3, k3);
      float sc = (s0 + s1) + (s2 + s3);  // score in log2 units
      if (__any(sc > m + 8.f)) {         // defer-max: rare after first key
        float mn = fmaxf(m, sc);
        float r = __builtin_amdgcn_exp2f(m - mn);
        l *= r;
        scale4(a0, r); scale4(a1, r); scale4(a2, r); scale4(a3, r);
        m = mn;
      }
      float p = __builtin_amdgcn_exp2f(sc - m);
      l += p;
      float4 v0 = kvl[512 + key * 4 + 0], v1 = kvl[512 + key * 4 + 1],
             v2 = kvl[512 + key * 4 + 2], v3 = kvl[512 + key * 4 + 3];
      fma4(a0, p, v0); fma4(a1, p, v1); fma4(a2, p, v2); fma4(a3, p, v3);
    }
    __syncthreads();  // all reads of chunk c done
    if (c < 3) {      // commit prefetched chunk c+1
      kvl[t] = pk0; kvl[t + 256] = pk1; kvl[512 + t] = pv0; kvl[512 + t + 256] = pv1;
    }
  }
  if (valid) {
    float inv = 1.f / l;
    scale4(a0, inv); scale4(a1, inv); scale4(a2, inv); scale4(a3, inv);
    float* orow = P.ob[s] + (size_t)row * C + head * 16;
    ((float4*)orow)[0] = a0; ((float4*)orow)[1] = a1;
    ((float4*)orow)[2] = a2; ((float4*)orow)[3] = a3;
  }
}

__global__ __launch_bounds__(256, 4) void attn_all(Params P) {
  __shared__ float4 kvlds[1024];  // 16 KB: 128-key K chunk + V chunk
  int bid = blockIdx.x;
  if (bid < 512)      attn_stage<32, 2>(P, 0, bid, kvlds);
  else if (bid < 640) attn_stage<64, 4>(P, 1, bid - 512, kvlds);
  else if (bid < 672) attn_stage<128, 8>(P, 2, bid - 640, kvlds);
  else                attn_stage<256, 16>(P, 3, bid - 672, kvlds);
}

// ---------------- Proj + residual + LayerNorm: RB=2048/C rows per block, ~9 KB LDS ----------------
template <int C>
__device__ void proj_stage(const Params& P, int s, int tile, float* olds) {
  constexpr int CP = C + 4;      // +4 floats keeps 16B alignment, breaks bank aliasing
  constexpr int R = 256 / C;     // row-groups per pass
  constexpr int NR = 8;          // rows per thread
  constexpr int RB = 2048 / C;   // rows per block
  int r0 = tile * RB;
  int t = threadIdx.x;
  const float4* __restrict__ obv = (const float4*)(P.ob[s] + (size_t)r0 * C);
  for (int i = t; i < 512; i += 256) {
    int row = i / (C / 4), kk = i % (C / 4);
    ((float4*)(olds + row * CP))[kk] = obv[i];
  }
  __syncthreads();
  int j = t % C, rg = t / C;
  const float* __restrict__ pw = P.pw[s];
  float acc[NR];
  #pragma unroll
  for (int i = 0; i < NR; ++i) acc[i] = 0.f;
  for (int k = 0; k < C; k += 4) {
    float4 w4 = *(const float4*)(pw + (size_t)j * C + k);
    #pragma unroll
    for (int i = 0; i < NR; ++i) {
      float4 o4 = *(const float4*)(olds + (rg + i * R) * CP + k);
      acc[i] = fmaf(o4.x, w4.x, acc[i]);
      acc[i] = fmaf(o4.y, w4.y, acc[i]);
      acc[i] = fmaf(o4.z, w4.z, acc[i]);
      acc[i] = fmaf(o4.w, w4.w, acc[i]);
    }
  }
  __syncthreads();  // all proj reads of olds done
  float pbj = P.pb[s][j];
  const float* __restrict__ x = P.x[s];
  #pragma unroll
  for (int i = 0; i < NR; ++i) {
    int r = rg + i * R;
    float xv = x[(size_t)(r0 + r) * C + j];
    olds[r * CP + j] = 0.5f * (acc[i] + pbj) + 0.5f * xv;
  }
  __syncthreads();
  // LayerNorm: one wave handles RB/4 rows
  int lane = t & 63, wv = t >> 6;
  const float* __restrict__ g = P.g[s];
  const float* __restrict__ lb = P.lb[s];
  float* __restrict__ out = P.out[s];
  #pragma unroll
  for (int rr = 0; rr < RB / 4; ++rr) {
    int r = wv * (RB / 4) + rr;
    float sum = 0.f, sq = 0.f;
    #pragma unroll
    for (int ch = lane; ch < C; ch += 64) {
      float v = olds[r * CP + ch];
      sum += v; sq = fmaf(v, v, sq);
    }
    #pragma unroll
    for (int o = 32; o; o >>= 1) { sum += __shfl_xor(sum, o); sq += __shfl_xor(sq, o); }
    float mu = sum * (1.f / C);
    float var = sq * (1.f / C) - mu * mu;
    float rstd = rsqrtf(var + 1e-5f);
    #pragma unroll
    for (int ch = lane; ch < C; ch += 64) {
      float v = (olds[r * CP + ch] - mu) * rstd;
      out[(size_t)(r0 + r) * C + ch] = fmaf(v, g[ch], lb[ch]);
    }
  }
}

__global__ __launch_bounds__(256) void proj_ln_all(Params P) {
  __shared__ float olds[2304];  // max over stages: RB*(C+4) floats
  int bid = blockIdx.x;
  if (bid < 1024)      proj_stage<32>(P, 0, bid, olds);
  else if (bid < 1280) proj_stage<64>(P, 1, bid - 1024, olds);
  else if (bid < 1344) proj_stage<128>(P, 2, bid - 1280, olds);
  else                 proj_stage<256>(P, 3, bid - 1344, olds);
}

extern "C" void kernel_launch(void* const* d_in, const int* in_sizes, int n_in,
                              void* d_out, int out_size, void* d_ws, size_t ws_size,
                              hipStream_t stream) {
  Params P;
  float* ws = (float*)d_ws;
  float* out = (float*)d_out;
  // ws layout (floats): K/V per stage, then attention-output buffers
  const size_t kvoff[4]  = {0, 32768, 98304, 229376};
  const size_t ksz[4]    = {16384, 32768, 65536, 131072};      // 512*c
  const size_t ooff[4]   = {491520, 2588672, 3112960, 3244032};
  const size_t outoff[4] = {0, 2097152, 2621440, 2752512};
  for (int i = 0; i < 4; ++i) {
    const int b = i * 8;
    P.x[i]   = (const float*)d_in[b + 0];
    P.f[i]   = (const float*)d_in[b + 1];
    P.kvw[i] = (const float*)d_in[b + 2];
    P.kvb[i] = (const float*)d_in[b + 3];
    P.pw[i]  = (const float*)d_in[b + 4];
    P.pb[i]  = (const float*)d_in[b + 5];
    P.g[i]   = (const float*)d_in[b + 6];
    P.lb[i]  = (const float*)d_in[b + 7];
    P.kb[i]  = ws + kvoff[i];
    P.vb[i]  = ws + kvoff[i] + ksz[i];
    P.ob[i]  = ws + ooff[i];
    P.out[i] = out + outoff[i];
  }
  // passthrough outputs (x4, x5)
  hipMemcpyAsync(out + 2785280, d_in[32], 5120 * sizeof(float), hipMemcpyDeviceToDevice, stream);
  hipMemcpyAsync(out + 2790400, d_in[33], 640 * sizeof(float), hipMemcpyDeviceToDevice, stream);

  kv_all<<<120, 256, 0, stream>>>(P);
  attn_all<<<688, 256, 0, stream>>>(P);
  proj_ln_all<<<1360, 256, 0, stream>>>(P);
}

// Round 5
// 318.358 us; speedup vs baseline: 1.6171x; 1.1154x over previous
//
#include <hip/hip_runtime.h>

#define LOG2E 1.44269504088896340736f

typedef float v4f __attribute__((ext_vector_type(4)));

struct Params {
  const float* x[4]; const float* f[4]; const float* kvw[4]; const float* kvb[4];
  const float* pw[4]; const float* pb[4]; const float* g[4]; const float* lb[4];
  float* kb[4]; float* ob[4]; float* out[4];
};

__device__ inline v4f fmav(v4f a, v4f b, v4f c) { return a * b + c; }

// ---------------- KV projection: packed layout kb[head][key][0:16]=K, [16:32]=V ----------------
__global__ __launch_bounds__(256) void kv_all(Params P) {
  int bid = blockIdx.x;
  int s, local;
  if (bid < 8)       { s = 0; local = bid; }
  else if (bid < 24) { s = 1; local = bid - 8; }
  else if (bid < 56) { s = 2; local = bid - 24; }
  else               { s = 3; local = bid - 56; }
  const int C = 32 << s;
  int nt = local & 7, jt = local >> 3;
  int n0 = nt * 64, j0 = jt * 64;
  const float* __restrict__ f = P.f[s];
  const float* __restrict__ w = P.kvw[s];
  __shared__ float fa[64][17];
  __shared__ float wb[64][17];
  int t = threadIdx.x;
  int ti = t & 15, tj = t >> 4;
  float acc[4][4];
  #pragma unroll
  for (int a = 0; a < 4; a++)
    #pragma unroll
    for (int b = 0; b < 4; b++) acc[a][b] = 0.f;

  for (int k0 = 0; k0 < C; k0 += 16) {
    __syncthreads();
    for (int i = t; i < 1024; i += 256) {
      int r = i >> 4, kk = i & 15;
      fa[r][kk] = f[(n0 + r) * C + k0 + kk];
      wb[r][kk] = w[(j0 + r) * C + k0 + kk];
    }
    __syncthreads();
    #pragma unroll
    for (int kk = 0; kk < 16; ++kk) {
      float av[4], bv[4];
      #pragma unroll
      for (int ii = 0; ii < 4; ii++) av[ii] = fa[ti * 4 + ii][kk];
      #pragma unroll
      for (int jj = 0; jj < 4; jj++) bv[jj] = wb[tj * 4 + jj][kk];
      #pragma unroll
      for (int ii = 0; ii < 4; ii++)
        #pragma unroll
        for (int jj = 0; jj < 4; jj++)
          acc[ii][jj] = fmaf(av[ii], bv[jj], acc[ii][jj]);
    }
  }
  const float* __restrict__ bias = P.kvb[s];
  float* kb = P.kb[s];
  #pragma unroll
  for (int ii = 0; ii < 4; ii++) {
    int n = n0 + ti * 4 + ii;
    #pragma unroll
    for (int jj = 0; jj < 4; jj++) {
      int j = j0 + tj * 4 + jj;
      float val = acc[ii][jj] + bias[j];
      if (j < C) {
        kb[(j >> 4) * 16384 + n * 32 + (j & 15)] = val;          // K slot
      } else {
        int j2 = j - C;
        kb[(j2 >> 4) * 16384 + n * 32 + 16 + (j2 & 15)] = val;   // V slot
      }
    }
  }
}

// ---------------- Attention: 128 threads/block, 2 query rows per lane ----------------
// K/V (packed 128B rows) streamed through a 16 KB LDS chunk (128 keys), register-prefetched.
// Broadcast LDS reads serve BOTH rows -> halves LDS-pipe pressure vs 1 row/lane.
template <int C, int H>
__device__ void attn_stage(const Params& P, int s, int local, v4f* kvl) {
  constexpr int ROWS = 2 * ((C == 32) ? 32768 : (C == 64) ? 4096 : (C == 128) ? 512 : 64);
  int tile = local / H, head = local % H;
  const v4f* __restrict__ kvh = (const v4f*)(P.kb[s] + head * 16384);  // 512 keys * 8 v4f
  int t = threadIdx.x;
  int rowA = tile * 256 + t, rowB = rowA + 128;
  bool vA = rowA < ROWS, vB = rowB < ROWS;
  int rA = vA ? rowA : (ROWS - 1), rB = vB ? rowB : (ROWS - 1);

  const v4f* xa = (const v4f*)(P.x[s] + (size_t)rA * C + head * 16);
  const v4f* xb = (const v4f*)(P.x[s] + (size_t)rB * C + head * 16);
  const float qs = 0.25f * LOG2E;  // head_dim^-0.5 folded with log2(e)
  v4f qa0 = xa[0] * qs, qa1 = xa[1] * qs, qa2 = xa[2] * qs, qa3 = xa[3] * qs;
  v4f qb0 = xb[0] * qs, qb1 = xb[1] * qs, qb2 = xb[2] * qs, qb3 = xb[3] * qs;

  float ma = -1e30f, la = 0.f, mb = -1e30f, lb = 0.f;
  v4f aa0 = 0.f, aa1 = 0.f, aa2 = 0.f, aa3 = 0.f;
  v4f ab0 = 0.f, ab1 = 0.f, ab2 = 0.f, ab3 = 0.f;

  // prefetch chunk 0: 1024 v4f (128 keys x 8), 8 per thread
  v4f pk[8];
  #pragma unroll
  for (int j = 0; j < 8; ++j) pk[j] = kvh[t + 128 * j];
  #pragma unroll
  for (int j = 0; j < 8; ++j) kvl[t + 128 * j] = pk[j];

  for (int c = 0; c < 4; ++c) {
    if (c < 3) {  // issue next-chunk loads early; latency hides under compute
      const v4f* src = kvh + (c + 1) * 1024;
      #pragma unroll
      for (int j = 0; j < 8; ++j) pk[j] = src[t + 128 * j];
    }
    __syncthreads();  // LDS chunk c visible
    #pragma unroll 2
    for (int kl = 0; kl < 128; ++kl) {
      const v4f* row = kvl + kl * 8;
      v4f k0 = row[0], k1 = row[1], k2 = row[2], k3 = row[3];
      v4f ta = qa0 * k0; ta = fmav(qa1, k1, ta); ta = fmav(qa2, k2, ta); ta = fmav(qa3, k3, ta);
      v4f tb = qb0 * k0; tb = fmav(qb1, k1, tb); tb = fmav(qb2, k2, tb); tb = fmav(qb3, k3, tb);
      float sa = (ta.x + ta.y) + (ta.z + ta.w);   // scores in log2 units
      float sb = (tb.x + tb.y) + (tb.z + tb.w);
      if (__any(fmaxf(sa - ma, sb - mb) > 8.f)) { // defer-max: rare after first keys
        float mna = fmaxf(ma, sa);
        float ra = __builtin_amdgcn_exp2f(ma - mna);
        la *= ra; aa0 *= ra; aa1 *= ra; aa2 *= ra; aa3 *= ra; ma = mna;
        float mnb = fmaxf(mb, sb);
        float rb = __builtin_amdgcn_exp2f(mb - mnb);
        lb *= rb; ab0 *= rb; ab1 *= rb; ab2 *= rb; ab3 *= rb; mb = mnb;
      }
      float pa = __builtin_amdgcn_exp2f(sa - ma);
      float pb = __builtin_amdgcn_exp2f(sb - mb);
      la += pa; lb += pb;
      v4f v0 = row[4], v1 = row[5], v2 = row[6], v3 = row[7];
      aa0 = fmav(pa, v0, aa0); aa1 = fmav(pa, v1, aa1);
      aa2 = fmav(pa, v2, aa2); aa3 = fmav(pa, v3, aa3);
      ab0 = fmav(pb, v0, ab0); ab1 = fmav(pb, v1, ab1);
      ab2 = fmav(pb, v2, ab2); ab3 = fmav(pb, v3, ab3);
    }
    __syncthreads();  // all reads of chunk c done
    if (c < 3) {      // commit prefetched chunk c+1
      #pragma unroll
      for (int j = 0; j < 8; ++j) kvl[t + 128 * j] = pk[j];
    }
  }
  if (vA) {
    float inv = 1.f / la;
    v4f* o = (v4f*)(P.ob[s] + (size_t)rowA * C + head * 16);
    o[0] = aa0 * inv; o[1] = aa1 * inv; o[2] = aa2 * inv; o[3] = aa3 * inv;
  }
  if (vB) {
    float inv = 1.f / lb;
    v4f* o = (v4f*)(P.ob[s] + (size_t)rowB * C + head * 16);
    o[0] = ab0 * inv; o[1] = ab1 * inv; o[2] = ab2 * inv; o[3] = ab3 * inv;
  }
}

__global__ __launch_bounds__(128) void attn_all(Params P) {
  __shared__ v4f kvlds[1024];  // 16 KB: 128-key packed K|V chunk
  int bid = blockIdx.x;
  if (bid < 512)      attn_stage<32, 2>(P, 0, bid, kvlds);
  else if (bid < 640) attn_stage<64, 4>(P, 1, bid - 512, kvlds);
  else if (bid < 672) attn_stage<128, 8>(P, 2, bid - 640, kvlds);
  else                attn_stage<256, 16>(P, 3, bid - 672, kvlds);
}

// ---------------- Passthrough copies (replaces SDMA memcpy nodes) ----------------
__global__ __launch_bounds__(256) void copy_pass(const float4* __restrict__ x4,
                                                 const float4* __restrict__ x5,
                                                 float4* __restrict__ o) {
  int i = blockIdx.x * 256 + threadIdx.x;
  if (i < 1280)      o[i] = x4[i];
  else if (i < 1440) o[i] = x5[i - 1280];
}

// ---------------- Proj + residual + LayerNorm: RB=2048/C rows per block, ~9 KB LDS ----------------
template <int C>
__device__ void proj_stage(const Params& P, int s, int tile, float* olds) {
  constexpr int CP = C + 4;      // +4 floats keeps 16B alignment, breaks bank aliasing
  constexpr int R = 256 / C;     // row-groups per pass
  constexpr int NR = 8;          // rows per thread
  constexpr int RB = 2048 / C;   // rows per block
  int r0 = tile * RB;
  int t = threadIdx.x;
  const float4* __restrict__ obv = (const float4*)(P.ob[s] + (size_t)r0 * C);
  for (int i = t; i < 512; i += 256) {
    int row = i / (C / 4), kk = i % (C / 4);
    ((float4*)(olds + row * CP))[kk] = obv[i];
  }
  __syncthreads();
  int j = t % C, rg = t / C;
  const float* __restrict__ pw = P.pw[s];
  float acc[NR];
  #pragma unroll
  for (int i = 0; i < NR; ++i) acc[i] = 0.f;
  for (int k = 0; k < C; k += 4) {
    float4 w4 = *(const float4*)(pw + (size_t)j * C + k);
    #pragma unroll
    for (int i = 0; i < NR; ++i) {
      float4 o4 = *(const float4*)(olds + (rg + i * R) * CP + k);
      acc[i] = fmaf(o4.x, w4.x, acc[i]);
      acc[i] = fmaf(o4.y, w4.y, acc[i]);
      acc[i] = fmaf(o4.z, w4.z, acc[i]);
      acc[i] = fmaf(o4.w, w4.w, acc[i]);
    }
  }
  __syncthreads();  // all proj reads of olds done
  float pbj = P.pb[s][j];
  const float* __restrict__ x = P.x[s];
  #pragma unroll
  for (int i = 0; i < NR; ++i) {
    int r = rg + i * R;
    float xv = x[(size_t)(r0 + r) * C + j];
    olds[r * CP + j] = 0.5f * (acc[i] + pbj) + 0.5f * xv;
  }
  __syncthreads();
  // LayerNorm: one wave handles RB/4 rows
  int lane = t & 63, wv = t >> 6;
  const float* __restrict__ g = P.g[s];
  const float* __restrict__ lb = P.lb[s];
  float* __restrict__ out = P.out[s];
  #pragma unroll
  for (int rr = 0; rr < RB / 4; ++rr) {
    int r = wv * (RB / 4) + rr;
    float sum = 0.f, sq = 0.f;
    #pragma unroll
    for (int ch = lane; ch < C; ch += 64) {
      float v = olds[r * CP + ch];
      sum += v; sq = fmaf(v, v, sq);
    }
    #pragma unroll
    for (int o = 32; o; o >>= 1) { sum += __shfl_xor(sum, o); sq += __shfl_xor(sq, o); }
    float mu = sum * (1.f / C);
    float var = sq * (1.f / C) - mu * mu;
    float rstd = rsqrtf(var + 1e-5f);
    #pragma unroll
    for (int ch = lane; ch < C; ch += 64) {
      float v = (olds[r * CP + ch] - mu) * rstd;
      out[(size_t)(r0 + r) * C + ch] = fmaf(v, g[ch], lb[ch]);
    }
  }
}

__global__ __launch_bounds__(256) void proj_ln_all(Params P) {
  __shared__ float olds[2304];  // max over stages: RB*(C+4) floats
  int bid = blockIdx.x;
  if (bid < 1024)      proj_stage<32>(P, 0, bid, olds);
  else if (bid < 1280) proj_stage<64>(P, 1, bid - 1024, olds);
  else if (bid < 1344) proj_stage<128>(P, 2, bid - 1280, olds);
  else                 proj_stage<256>(P, 3, bid - 1344, olds);
}

extern "C" void kernel_launch(void* const* d_in, const int* in_sizes, int n_in,
                              void* d_out, int out_size, void* d_ws, size_t ws_size,
                              hipStream_t stream) {
  Params P;
  float* ws = (float*)d_ws;
  float* out = (float*)d_out;
  // ws layout (floats): packed K|V per stage, then attention-output buffers
  const size_t kvoff[4]  = {0, 32768, 98304, 229376};
  const size_t ooff[4]   = {491520, 2588672, 3112960, 3244032};
  const size_t outoff[4] = {0, 2097152, 2621440, 2752512};
  for (int i = 0; i < 4; ++i) {
    const int b = i * 8;
    P.x[i]   = (const float*)d_in[b + 0];
    P.f[i]   = (const float*)d_in[b + 1];
    P.kvw[i] = (const float*)d_in[b + 2];
    P.kvb[i] = (const float*)d_in[b + 3];
    P.pw[i]  = (const float*)d_in[b + 4];
    P.pb[i]  = (const float*)d_in[b + 5];
    P.g[i]   = (const float*)d_in[b + 6];
    P.lb[i]  = (const float*)d_in[b + 7];
    P.kb[i]  = ws + kvoff[i];
    P.ob[i]  = ws + ooff[i];
    P.out[i] = out + outoff[i];
  }

  copy_pass<<<6, 256, 0, stream>>>((const float4*)d_in[32], (const float4*)d_in[33],
                                   (float4*)(out + 2785280));
  kv_all<<<120, 256, 0, stream>>>(P);
  attn_all<<<688, 128, 0, stream>>>(P);
  proj_ln_all<<<1360, 256, 0, stream>>>(P);
}